// Round 11
// baseline (398.976 us; speedup 1.0000x reference)
//
#include <hip/hip_runtime.h>

typedef float f32x4 __attribute__((ext_vector_type(4)));
typedef __bf16 bf16x8 __attribute__((ext_vector_type(8)));
typedef unsigned short u16;

#define DIM 2048
#define SEQ 1024
#define BSZ 2
#define NH 16
#define NKV 4
#define HD 128
#define FFNDIM 5632
#define MROWS (BSZ * SEQ)  // 2048

__device__ __forceinline__ u16 f2bf(float f) {
  union { float f; unsigned u; } v; v.f = f;
  unsigned u = v.u;
  unsigned r = (u + 0x7fffu + ((u >> 16) & 1u)) >> 16;  // RNE
  return (u16)r;
}
__device__ __forceinline__ float bf2f(u16 h) {
  union { unsigned u; float f; } v; v.u = ((unsigned)h) << 16; return v.f;
}

__device__ __forceinline__ void gld16(const void* g, void* l) {
  __builtin_amdgcn_global_load_lds(
      (const __attribute__((address_space(1))) unsigned int*)g,
      (__attribute__((address_space(3))) unsigned int*)l, 16, 0, 0);
}

// ---------- transpose + fp32->bf16 convert: W [K][N] f32 -> Wt[(n*rs+ro)][K] bf16
__global__ __launch_bounds__(256) void kxpose(const float* __restrict__ W,
                                              u16* __restrict__ Wt,
                                              int K, int N, int rs, int ro) {
  __shared__ float t[64][65];
  int kb = blockIdx.y * 64, nb = blockIdx.x * 64;
  int tid = threadIdx.x;
#pragma unroll
  for (int it = 0; it < 16; ++it) {
    int idx = it * 256 + tid;
    int r = idx >> 6, c = idx & 63;
    t[r][c] = W[(size_t)(kb + r) * N + nb + c];
  }
  __syncthreads();
#pragma unroll
  for (int it = 0; it < 16; ++it) {
    int idx = it * 256 + tid;
    int rn = idx >> 6, ck = idx & 63;
    Wt[((size_t)(nb + rn) * rs + ro) * K + kb + ck] = f2bf(t[ck][rn]);
  }
}

// ---------- V transpose: v [b*S+s][g*128+d] bf16 -> Vt [((b*4+g)*128+d)*S + s]
__global__ __launch_bounds__(256) void kvxpose(const u16* __restrict__ v,
                                               u16* __restrict__ vt) {
  __shared__ u16 t[64][66];
  int bg = blockIdx.z;
  int b = bg >> 2, g = bg & 3;
  int s0 = blockIdx.x * 64, d0 = blockIdx.y * 64;
  int tid = threadIdx.x;
  int rr = tid >> 4, cc = (tid & 15) * 4;
#pragma unroll
  for (int it = 0; it < 4; ++it) {
    int r = it * 16 + rr;
    *(uint2*)&t[r][cc] =
        *(const uint2*)(v + (size_t)(b * SEQ + s0 + r) * (NKV * HD) + g * HD + d0 + cc);
  }
  __syncthreads();
#pragma unroll
  for (int it = 0; it < 4; ++it) {
    int r = it * 16 + rr;  // d index within tile
    u16 o[4] = {t[cc][r], t[cc + 1][r], t[cc + 2][r], t[cc + 3][r]};
    *(uint2*)(vt + (size_t)((b * NKV + g) * HD + d0 + r) * SEQ + s0 + cc) = *(const uint2*)o;
  }
}

// ---------- RMSNorm: x [rows][2048] f32 -> out bf16
__global__ __launch_bounds__(256) void krmsnorm(const float* __restrict__ x,
                                                const float* __restrict__ w,
                                                u16* __restrict__ out) {
  int row = blockIdx.x, tid = threadIdx.x;
  const float* xr = x + (size_t)row * DIM;
  float4 a = *(const float4*)(xr + tid * 8);
  float4 b = *(const float4*)(xr + tid * 8 + 4);
  float ss = a.x * a.x + a.y * a.y + a.z * a.z + a.w * a.w +
             b.x * b.x + b.y * b.y + b.z * b.z + b.w * b.w;
#pragma unroll
  for (int off = 1; off < 64; off <<= 1) ss += __shfl_xor(ss, off, 64);
  __shared__ float red[4];
  if ((tid & 63) == 0) red[tid >> 6] = ss;
  __syncthreads();
  float tot = red[0] + red[1] + red[2] + red[3];
  float sc = rsqrtf(tot * (1.0f / DIM) + 1e-5f);
  float xs[8] = {a.x, a.y, a.z, a.w, b.x, b.y, b.z, b.w};
  const float* wr = w + tid * 8;
  u16 o[8];
#pragma unroll
  for (int j = 0; j < 8; ++j) o[j] = f2bf(xs[j] * sc * wr[j]);
  *(int4*)(out + (size_t)row * DIM + tid * 8) = *(const int4*)o;
}

// ---------- GEMM 128x128, 8 waves (2Mx4N, wave tile 64x32):
// C[2048][N] = A[2048][K](bf16) * Bt[N][K](bf16)^T
// Counted-vmcnt pipeline + XOR-swizzled LDS (validated r5-r10)
// + XCD-aware block swizzle (T1; all grids divisible by 8).
// EPI 0: qkv-route with FUSED RoPE (q,k) + f32 cache_k; EPI 2: f32 = acc + res
template <int EPI>
__global__ __launch_bounds__(512, 4) void kgemm(
    const u16* __restrict__ A, const u16* __restrict__ Bt, int N, int K,
    u16* o0, u16* __restrict__ o1, u16* __restrict__ o2,
    float* of, const float* res, const float* __restrict__ fc) {
  __shared__ u16 As[2][128 * 64];
  __shared__ u16 Bs[2][128 * 64];
  // XCD swizzle: contiguous chunk of the x-major grid per XCD
  int nwg = gridDim.x * gridDim.y;
  int lin = blockIdx.y * gridDim.x + blockIdx.x;
  int cpx = nwg >> 3;
  int swzb = (lin & 7) * cpx + (lin >> 3);
  int bn = (swzb % gridDim.x) * 128, bm = (swzb / gridDim.x) * 128;
  int tid = threadIdx.x, lane = tid & 63, wv = tid >> 6;  // 8 waves
  int wm = (wv >> 2) * 64;   // 0 / 64
  int wn = (wv & 3) * 32;    // 0..96
  int r16 = lane & 15, grp = lane >> 4;
  int srow = lane >> 3;                    // 0..7: row within 8-row chunk
  int schunk = ((lane & 7) ^ srow) * 8;    // inverse-swizzled source k-offset
  f32x4 acc[4][2] = {};
  // wave wv stages rows [wv*16, wv*16+16) of both tiles
  const u16* Abase = A + (size_t)(bm + wv * 16) * K + schunk;
  const u16* Bbase = Bt + (size_t)(bn + wv * 16) * K + schunk;
  int woff = wv * 16 * 64;

  auto STAGE = [&](int buf, int k0) {
#pragma unroll
    for (int j = 0; j < 2; ++j) {
      gld16(Abase + (size_t)(j * 8 + srow) * K + k0, &As[buf][woff + j * 512]);
      gld16(Bbase + (size_t)(j * 8 + srow) * K + k0, &Bs[buf][woff + j * 512]);
    }
  };
  auto COMPUTE = [&](int buf) {
#pragma unroll
    for (int kk = 0; kk < 2; ++kk) {
      int swz = (((kk << 2) | grp) ^ (r16 & 7)) * 8;
      bf16x8 af[4], bfr[2];
#pragma unroll
      for (int m = 0; m < 4; ++m)
        af[m] = *(const bf16x8*)&As[buf][(wm + m * 16 + r16) * 64 + swz];
#pragma unroll
      for (int n = 0; n < 2; ++n)
        bfr[n] = *(const bf16x8*)&Bs[buf][(wn + n * 16 + r16) * 64 + swz];
#pragma unroll
      for (int m = 0; m < 4; ++m)
#pragma unroll
        for (int n = 0; n < 2; ++n)
          acc[m][n] = __builtin_amdgcn_mfma_f32_16x16x32_bf16(af[m], bfr[n], acc[m][n], 0, 0, 0);
    }
  };

  STAGE(0, 0);
  int nt = K >> 6;
  for (int t = 0; t < nt; ++t) {
    int cur = t & 1;
    if (t + 1 < nt) {
      STAGE(cur ^ 1, (t + 1) << 6);
      asm volatile("s_waitcnt vmcnt(4)" ::: "memory");
    } else {
      asm volatile("s_waitcnt vmcnt(0)" ::: "memory");
    }
    __builtin_amdgcn_sched_barrier(0);
    __builtin_amdgcn_s_barrier();   // tile t visible to all waves
    __builtin_amdgcn_sched_barrier(0);
    COMPUTE(cur);
    __builtin_amdgcn_s_barrier();   // all waves done reading buf[cur]
  }

  bool oddlane = (r16 & 1) != 0;
#pragma unroll
  for (int mi = 0; mi < 4; ++mi) {
#pragma unroll
    for (int ni = 0; ni < 2; ++ni) {
#pragma unroll
      for (int r = 0; r < 4; ++r) {
        int gr = bm + wm + mi * 16 + grp * 4 + r;
        int gc = bn + wn + ni * 16 + r16;
        float v = acc[mi][ni][r];
        if constexpr (EPI == 0) {
          float pv = __shfl_xor(v, 1, 64);  // partner column (pair 2j<->2j+1)
          if (gc < DIM + 512) {
            // fused RoPE: lane pair (even=x0, odd=x1)
            int s_idx = gr & (SEQ - 1);
            int jp = (gc & 127) >> 1;
            float2 cs = *(const float2*)(fc + s_idx * HD + jp * 2);
            float y;
            if (oddlane) y = pv * cs.y + v * cs.x;   // x0*sin + x1*cos
            else         y = v * cs.x - pv * cs.y;   // x0*cos - x1*sin
            if (gc < DIM) {
              o0[(size_t)gr * DIM + gc] = f2bf(y);          // q (roped)
            } else {
              int c2 = gc - DIM;
              o1[(size_t)gr * 512 + c2] = f2bf(y);          // k (roped)
              res ? (void)0 : (void)0;
              ((float*)res)[(size_t)gr * 512 + c2] = y;     // cache_k f32
            }
          } else {
            int c2 = gc - (DIM + 512);
            of[(size_t)gr * 512 + c2] = v;                  // cache_v f32
            o2[(size_t)gr * 512 + c2] = f2bf(v);            // v bf16
          }
        } else {
          of[(size_t)gr * N + gc] = v + res[(size_t)gr * N + gc];
        }
      }
    }
  }
}

// ---------- interleaved gate/up GEMM, 128x128 tile, 8 waves.
// Bt rows: 2j = wg^T[:,j], 2j+1 = wu^T[:,j]  (N_wide = 11264).
// Epilogue: lane pairs (even=gate, odd=up) exchanged via shfl_xor(1);
// even lanes store silu(g)*u.  XCD-aware block swizzle (T1).
__global__ __launch_bounds__(512, 4) void kgemm_gu(
    const u16* __restrict__ A, const u16* __restrict__ Bt,
    u16* __restrict__ out) {
  const int K = DIM;
  __shared__ u16 As[2][128 * 64];
  __shared__ u16 Bs[2][128 * 64];
  int nwg = gridDim.x * gridDim.y;
  int lin = blockIdx.y * gridDim.x + blockIdx.x;
  int cpx = nwg >> 3;
  int swzb = (lin & 7) * cpx + (lin >> 3);
  int bn = (swzb % gridDim.x) * 128, bm = (swzb / gridDim.x) * 128;
  int tid = threadIdx.x, lane = tid & 63, wv = tid >> 6;
  int wm = (wv >> 2) * 64;
  int wn = (wv & 3) * 32;
  int r16 = lane & 15, grp = lane >> 4;
  int srow = lane >> 3;
  int schunk = ((lane & 7) ^ srow) * 8;
  f32x4 acc[4][2] = {};
  const u16* Abase = A + (size_t)(bm + wv * 16) * K + schunk;
  const u16* Bbase = Bt + (size_t)(bn + wv * 16) * K + schunk;
  int woff = wv * 16 * 64;

  auto STAGE = [&](int buf, int k0) {
#pragma unroll
    for (int j = 0; j < 2; ++j) {
      gld16(Abase + (size_t)(j * 8 + srow) * K + k0, &As[buf][woff + j * 512]);
      gld16(Bbase + (size_t)(j * 8 + srow) * K + k0, &Bs[buf][woff + j * 512]);
    }
  };
  auto COMPUTE = [&](int buf) {
#pragma unroll
    for (int kk = 0; kk < 2; ++kk) {
      int swz = (((kk << 2) | grp) ^ (r16 & 7)) * 8;
      bf16x8 af[4], bfr[2];
#pragma unroll
      for (int m = 0; m < 4; ++m)
        af[m] = *(const bf16x8*)&As[buf][(wm + m * 16 + r16) * 64 + swz];
#pragma unroll
      for (int n = 0; n < 2; ++n)
        bfr[n] = *(const bf16x8*)&Bs[buf][(wn + n * 16 + r16) * 64 + swz];
#pragma unroll
      for (int m = 0; m < 4; ++m)
#pragma unroll
        for (int n = 0; n < 2; ++n)
          acc[m][n] = __builtin_amdgcn_mfma_f32_16x16x32_bf16(af[m], bfr[n], acc[m][n], 0, 0, 0);
    }
  };

  STAGE(0, 0);
  int nt = K >> 6;
  for (int t = 0; t < nt; ++t) {
    int cur = t & 1;
    if (t + 1 < nt) {
      STAGE(cur ^ 1, (t + 1) << 6);
      asm volatile("s_waitcnt vmcnt(4)" ::: "memory");
    } else {
      asm volatile("s_waitcnt vmcnt(0)" ::: "memory");
    }
    __builtin_amdgcn_sched_barrier(0);
    __builtin_amdgcn_s_barrier();
    __builtin_amdgcn_sched_barrier(0);
    COMPUTE(cur);
    __builtin_amdgcn_s_barrier();
  }

  bool evenlane = (r16 & 1) == 0;
#pragma unroll
  for (int mi = 0; mi < 4; ++mi) {
#pragma unroll
    for (int ni = 0; ni < 2; ++ni) {
#pragma unroll
      for (int r = 0; r < 4; ++r) {
        float v = acc[mi][ni][r];
        float pv = __shfl_xor(v, 1, 64);  // partner column (gate<->up)
        if (evenlane) {
          int gr = bm + wm + mi * 16 + grp * 4 + r;
          int gc = bn + wn + ni * 16 + r16;
          float sg = v / (1.0f + __expf(-v));
          out[(size_t)gr * FFNDIM + (gc >> 1)] = f2bf(sg * pv);
        }
      }
    }
  }
}

// ---------- causal GQA flash attention, LDS-staged K/V.
// Block = 4 waves = 64 q-rows of one (b,h); sweeps KV in 64-tiles with
// double-buffered LDS staging (counted vmcnt, GEMM-proven skeleton) and
// GEMM-proven XOR-chunk swizzle. Longest blocks dispatch first.
__global__ __launch_bounds__(256) void kattn(const u16* __restrict__ qb,
                                             const u16* __restrict__ kb,
                                             const u16* __restrict__ vtb,
                                             u16* __restrict__ ctxb) {
  __shared__ u16 Ks[2][64 * 128];   // [t_rel][d] content-swizzled
  __shared__ u16 Vs[2][128 * 64];   // [d][t_rel] content-swizzled
  __shared__ u16 Plds[4][16][72];
  int tid = threadIdx.x;
  int l = tid & 63, wv = tid >> 6;
  int qg = 15 - blockIdx.x;  // longest first
  int h = blockIdx.y, b = blockIdx.z;
  int g = h >> 2;  // J = NH/NKV = 4
  int q0 = qg * 64 + wv * 16;
  int r16 = l & 15, grp = l >> 4;
  const float scale = 0.08838834764831845f;  // 1/sqrt(128)
  bf16x8 qf[4];
  {
    const u16* qrow = qb + (size_t)(b * SEQ + q0 + r16) * DIM + h * HD + grp * 8;
#pragma unroll
    for (int c = 0; c < 4; ++c) qf[c] = *(const bf16x8*)(qrow + c * 32);
  }
  const u16* kg = kb + (size_t)b * SEQ * (NKV * HD) + g * HD;
  const u16* vg = vtb + (size_t)((b * NKV + g) * HD) * SEQ;

  // stage one 64-KV tile: K 64x128 (4 passes) + V 128x64 (4 passes), 8 gld16/thread
  auto STAGE = [&](int buf, int t0) {
#pragma unroll
    for (int p = 0; p < 4; ++p) {
      int row = p * 16 + wv * 4 + (l >> 4);          // t_rel 0..63
      int ch = (l & 15) ^ (row & 7);                 // inverse swizzle
      gld16(kg + (size_t)(t0 + row) * (NKV * HD) + ch * 8,
            &Ks[buf][p * 2048 + wv * 512]);
    }
#pragma unroll
    for (int p = 0; p < 4; ++p) {
      int row = p * 32 + wv * 8 + (l >> 3);          // d 0..127
      int ch = (l & 7) ^ (row & 7);
      gld16(vg + (size_t)row * SEQ + t0 + ch * 8,
            &Vs[buf][p * 2048 + wv * 512]);
    }
  };

  f32x4 ctx[8] = {};
  float m = -1e30f, lsum = 0.0f;
  int q_idx = q0 + r16;
  int ntiles = qg + 1;

  STAGE(0, 0);
  for (int tt = 0; tt < ntiles; ++tt) {
    int cur = tt & 1;
    if (tt + 1 < ntiles) {
      STAGE(cur ^ 1, (tt + 1) * 64);
      asm volatile("s_waitcnt vmcnt(8)" ::: "memory");
    } else {
      asm volatile("s_waitcnt vmcnt(0)" ::: "memory");
    }
    __builtin_amdgcn_sched_barrier(0);
    __builtin_amdgcn_s_barrier();   // tile tt visible
    __builtin_amdgcn_sched_barrier(0);
    int t0 = tt * 64;
    f32x4 d[4] = {{0.f, 0.f, 0.f, 0.f}, {0.f, 0.f, 0.f, 0.f},
                  {0.f, 0.f, 0.f, 0.f}, {0.f, 0.f, 0.f, 0.f}};
    __builtin_amdgcn_s_setprio(1);
#pragma unroll
    for (int c = 0; c < 4; ++c) {
#pragma unroll
      for (int ch = 0; ch < 4; ++ch) {
        int row = ch * 16 + r16;
        bf16x8 kf = *(const bf16x8*)&Ks[cur][row * 128 + (((c * 4 + grp) ^ (row & 7)) * 8)];
        d[ch] = __builtin_amdgcn_mfma_f32_16x16x32_bf16(kf, qf[c], d[ch], 0, 0, 0);
      }
    }
    __builtin_amdgcn_s_setprio(0);
    // lane holds S[q = q0+r16][t = t0 + ch*16 + grp*4 + r]
    float p[16];
    float mx = -1e30f;
#pragma unroll
    for (int ch = 0; ch < 4; ++ch) {
#pragma unroll
      for (int r = 0; r < 4; ++r) {
        int tA = t0 + ch * 16 + grp * 4 + r;
        float s = d[ch][r] * scale;
        if (tA > q_idx) s = -1e30f;
        p[ch * 4 + r] = s;
        mx = fmaxf(mx, s);
      }
    }
    mx = fmaxf(mx, __shfl_xor(mx, 16, 64));
    mx = fmaxf(mx, __shfl_xor(mx, 32, 64));
    // defer-max: skip rescale when per-tile max growth <= 8 (P bounded by e^8)
    if (!__all(mx - m <= 8.0f)) {
      float mnew = fmaxf(m, mx);
      float corr = __expf(m - mnew);
      lsum *= corr;
      float cf[4];
#pragma unroll
      for (int r = 0; r < 4; ++r) cf[r] = __shfl(corr, grp * 4 + r, 64);
#pragma unroll
      for (int dc = 0; dc < 8; ++dc)
#pragma unroll
        for (int r = 0; r < 4; ++r) ctx[dc][r] *= cf[r];
      m = mnew;
    }
    float psum = 0.f;
#pragma unroll
    for (int i = 0; i < 16; ++i) {
      p[i] = __expf(p[i] - m);
      psum += p[i];
    }
    psum += __shfl_xor(psum, 16, 64);
    psum += __shfl_xor(psum, 32, 64);
    lsum += psum;
    // P -> per-wave LDS slab [q][t_rel]
#pragma unroll
    for (int ch = 0; ch < 4; ++ch) {
      unsigned w0 = (unsigned)f2bf(p[ch * 4]) | ((unsigned)f2bf(p[ch * 4 + 1]) << 16);
      unsigned w1 = (unsigned)f2bf(p[ch * 4 + 2]) | ((unsigned)f2bf(p[ch * 4 + 3]) << 16);
      *(unsigned*)&Plds[wv][r16][ch * 16 + grp * 4] = w0;
      *(unsigned*)&Plds[wv][r16][ch * 16 + grp * 4 + 2] = w1;
    }
    bf16x8 pa0, pa1;
    {
      union { bf16x8 v; int4 q; } u0, u1;
      u0.q = *(const int4*)&Plds[wv][r16][grp * 8];
      u1.q = *(const int4*)&Plds[wv][r16][32 + grp * 8];
      pa0 = u0.v;
      pa1 = u1.v;
    }
    __builtin_amdgcn_s_setprio(1);
#pragma unroll
    for (int dc = 0; dc < 8; ++dc) {
      int row = dc * 16 + r16;
      bf16x8 vf0 = *(const bf16x8*)&Vs[cur][row * 64 + ((grp ^ (row & 7)) * 8)];
      bf16x8 vf1 = *(const bf16x8*)&Vs[cur][row * 64 + (((grp + 4) ^ (row & 7)) * 8)];
      ctx[dc] = __builtin_amdgcn_mfma_f32_16x16x32_bf16(pa0, vf0, ctx[dc], 0, 0, 0);
      ctx[dc] = __builtin_amdgcn_mfma_f32_16x16x32_bf16(pa1, vf1, ctx[dc], 0, 0, 0);
    }
    __builtin_amdgcn_s_setprio(0);
    __builtin_amdgcn_s_barrier();   // all waves done reading Ks/Vs[cur]
  }
  float linv = 1.0f / lsum;
  float lf[4];
#pragma unroll
  for (int r = 0; r < 4; ++r) lf[r] = __shfl(linv, grp * 4 + r, 64);
  u16* crow = ctxb + (size_t)(b * SEQ + q0) * DIM + h * HD;
#pragma unroll
  for (int dc = 0; dc < 8; ++dc)
#pragma unroll
    for (int r = 0; r < 4; ++r)
      crow[(size_t)(grp * 4 + r) * DIM + dc * 16 + r16] = f2bf(ctx[dc][r] * lf[r]);
}

extern "C" void kernel_launch(void* const* d_in, const int* in_sizes, int n_in,
                              void* d_out, int out_size, void* d_ws, size_t ws_size,
                              hipStream_t stream) {
  const float* x = (const float*)d_in[0];
  const float* fc = (const float*)d_in[1];
  const float* wq = (const float*)d_in[5];
  const float* wk = (const float*)d_in[6];
  const float* wv = (const float*)d_in[7];
  const float* wo = (const float*)d_in[8];
  const float* wg = (const float*)d_in[9];
  const float* wu = (const float*)d_in[10];
  const float* wd = (const float*)d_in[11];
  const float* anw = (const float*)d_in[12];
  const float* fnw = (const float*)d_in[13];

  float* out_x = (float*)d_out;                       // [2048][2048] f32
  float* out_ck = out_x + (size_t)MROWS * DIM;        // [2048][512] f32
  float* out_cv = out_ck + (size_t)MROWS * NKV * HD;  // [2048][512] f32

  char* ws = (char*)d_ws;
  u16* h_b    = (u16*)(ws);                      // 8 MB   [2048][2048] bf16
  u16* q_b    = (u16*)(ws + (8u << 20));         // 8 MB   [2048][2048]
  u16* k_b    = (u16*)(ws + (16u << 20));        // 2 MB   [2048][512]
  u16* v_b    = (u16*)(ws + (18u << 20));        // 2 MB   [2048][512]
  u16* ctx_b  = (u16*)(ws + (20u << 20));        // 8 MB   [2048][2048]
  u16* hf_b   = (u16*)(ws + (28u << 20));        // 8 MB   [2048][2048]
  u16* Wt     = (u16*)(ws + (60u << 20));        // 12 MB  qkv^T, later wo^T
  u16* vt_b   = h_b;                             // reuse (attn phase)
  u16* Wt_gu  = (u16*)(ws + (36u << 20));        // 44 MB  [11264][2048] interleaved
  u16* g_b    = (u16*)(ws);                      // 22 MB  silu*up (post-attn)
  u16* Wt_dn  = (u16*)(ws + (36u << 20));        // 22 MB  wd^T (post-gu)

  // QKV weights -> Wt rows [0,2048)=wq^T, [2048,2560)=wk^T, [2560,3072)=wv^T
  kxpose<<<dim3(2048 / 64, 2048 / 64), 256, 0, stream>>>(wq, Wt, 2048, 2048, 1, 0);
  kxpose<<<dim3(512 / 64, 2048 / 64), 256, 0, stream>>>(wk, Wt + (size_t)2048 * 2048, 2048, 512, 1, 0);
  kxpose<<<dim3(512 / 64, 2048 / 64), 256, 0, stream>>>(wv, Wt + (size_t)2560 * 2048, 2048, 512, 1, 0);

  krmsnorm<<<MROWS, 256, 0, stream>>>(x, anw, h_b);
  // QKV GEMM with fused RoPE (q,k) + f32 cache writes (res slot carries out_ck)
  kgemm<0><<<dim3(3072 / 128, 16), 512, 0, stream>>>(h_b, Wt, 3072, 2048,
                                                     q_b, k_b, v_b, out_cv, out_ck, fc);
  kvxpose<<<dim3(SEQ / 64, HD / 64, BSZ * NKV), 256, 0, stream>>>(v_b, vt_b);
  kattn<<<dim3(SEQ / 64, NH, BSZ), 256, 0, stream>>>(q_b, k_b, vt_b, ctx_b);

  kxpose<<<dim3(32, 32), 256, 0, stream>>>(wo, Wt, 2048, 2048, 1, 0);
  kgemm<2><<<dim3(16, 16), 512, 0, stream>>>(ctx_b, Wt, 2048, 2048,
                                             nullptr, nullptr, nullptr, out_x, x, nullptr);
  krmsnorm<<<MROWS, 256, 0, stream>>>(out_x, fnw, hf_b);

  // FFN: interleaved gate/up -> fused swiglu epilogue -> down
  kxpose<<<dim3(5632 / 64, 2048 / 64), 256, 0, stream>>>(wg, Wt_gu, 2048, 5632, 2, 0);
  kxpose<<<dim3(5632 / 64, 2048 / 64), 256, 0, stream>>>(wu, Wt_gu, 2048, 5632, 2, 1);
  kgemm_gu<<<dim3(11264 / 128, 16), 512, 0, stream>>>(hf_b, Wt_gu, g_b);
  kxpose<<<dim3(2048 / 64, 5632 / 64), 256, 0, stream>>>(wd, Wt_dn, 5632, 2048, 1, 0);
  kgemm<2><<<dim3(16, 16), 512, 0, stream>>>(g_b, Wt_dn, 2048, 5632,
                                             nullptr, nullptr, nullptr, out_x, out_x, nullptr);
}

// Round 12
// 377.818 us; speedup vs baseline: 1.0560x; 1.0560x over previous
//
#include <hip/hip_runtime.h>

typedef float f32x4 __attribute__((ext_vector_type(4)));
typedef __bf16 bf16x8 __attribute__((ext_vector_type(8)));
typedef unsigned short u16;

#define DIM 2048
#define SEQ 1024
#define BSZ 2
#define NH 16
#define NKV 4
#define HD 128
#define FFNDIM 5632
#define MROWS (BSZ * SEQ)  // 2048

__device__ __forceinline__ u16 f2bf(float f) {
  union { float f; unsigned u; } v; v.f = f;
  unsigned u = v.u;
  unsigned r = (u + 0x7fffu + ((u >> 16) & 1u)) >> 16;  // RNE
  return (u16)r;
}
__device__ __forceinline__ float bf2f(u16 h) {
  union { unsigned u; float f; } v; v.u = ((unsigned)h) << 16; return v.f;
}

__device__ __forceinline__ void gld16(const void* g, void* l) {
  __builtin_amdgcn_global_load_lds(
      (const __attribute__((address_space(1))) unsigned int*)g,
      (__attribute__((address_space(3))) unsigned int*)l, 16, 0, 0);
}

// ---------- transpose + fp32->bf16 convert: W [K][N] f32 -> Wt[(n*rs+ro)][K] bf16
__global__ __launch_bounds__(256) void kxpose(const float* __restrict__ W,
                                              u16* __restrict__ Wt,
                                              int K, int N, int rs, int ro) {
  __shared__ float t[64][65];
  int kb = blockIdx.y * 64, nb = blockIdx.x * 64;
  int tid = threadIdx.x;
#pragma unroll
  for (int it = 0; it < 16; ++it) {
    int idx = it * 256 + tid;
    int r = idx >> 6, c = idx & 63;
    t[r][c] = W[(size_t)(kb + r) * N + nb + c];
  }
  __syncthreads();
#pragma unroll
  for (int it = 0; it < 16; ++it) {
    int idx = it * 256 + tid;
    int rn = idx >> 6, ck = idx & 63;
    Wt[((size_t)(nb + rn) * rs + ro) * K + kb + ck] = f2bf(t[ck][rn]);
  }
}

// ---------- V transpose: v [b*S+s][g*128+d] bf16 -> Vt [((b*4+g)*128+d)*S + s]
__global__ __launch_bounds__(256) void kvxpose(const u16* __restrict__ v,
                                               u16* __restrict__ vt) {
  __shared__ u16 t[64][66];
  int bg = blockIdx.z;
  int b = bg >> 2, g = bg & 3;
  int s0 = blockIdx.x * 64, d0 = blockIdx.y * 64;
  int tid = threadIdx.x;
  int rr = tid >> 4, cc = (tid & 15) * 4;
#pragma unroll
  for (int it = 0; it < 4; ++it) {
    int r = it * 16 + rr;
    *(uint2*)&t[r][cc] =
        *(const uint2*)(v + (size_t)(b * SEQ + s0 + r) * (NKV * HD) + g * HD + d0 + cc);
  }
  __syncthreads();
#pragma unroll
  for (int it = 0; it < 4; ++it) {
    int r = it * 16 + rr;  // d index within tile
    u16 o[4] = {t[cc][r], t[cc + 1][r], t[cc + 2][r], t[cc + 3][r]};
    *(uint2*)(vt + (size_t)((b * NKV + g) * HD + d0 + r) * SEQ + s0 + cc) = *(const uint2*)o;
  }
}

// ---------- RMSNorm: x [rows][2048] f32 -> out bf16
__global__ __launch_bounds__(256) void krmsnorm(const float* __restrict__ x,
                                                const float* __restrict__ w,
                                                u16* __restrict__ out) {
  int row = blockIdx.x, tid = threadIdx.x;
  const float* xr = x + (size_t)row * DIM;
  float4 a = *(const float4*)(xr + tid * 8);
  float4 b = *(const float4*)(xr + tid * 8 + 4);
  float ss = a.x * a.x + a.y * a.y + a.z * a.z + a.w * a.w +
             b.x * b.x + b.y * b.y + b.z * b.z + b.w * b.w;
#pragma unroll
  for (int off = 1; off < 64; off <<= 1) ss += __shfl_xor(ss, off, 64);
  __shared__ float red[4];
  if ((tid & 63) == 0) red[tid >> 6] = ss;
  __syncthreads();
  float tot = red[0] + red[1] + red[2] + red[3];
  float sc = rsqrtf(tot * (1.0f / DIM) + 1e-5f);
  float xs[8] = {a.x, a.y, a.z, a.w, b.x, b.y, b.z, b.w};
  const float* wr = w + tid * 8;
  u16 o[8];
#pragma unroll
  for (int j = 0; j < 8; ++j) o[j] = f2bf(xs[j] * sc * wr[j]);
  *(int4*)(out + (size_t)row * DIM + tid * 8) = *(const int4*)o;
}

// ---------- GEMM 128x128, 8 waves (2Mx4N, wave tile 64x32):
// C[2048][N] = A[2048][K](bf16) * Bt[N][K](bf16)^T
// Counted-vmcnt pipeline + XOR-swizzled LDS (validated r5-r10).
// Default blockIdx mapping (XCD chunk-swizzle REVERTED: it made every XCD
// stream the whole B matrix -> FETCH 104->368 MB, r11 post-mortem).
// EPI 0: qkv-route with FUSED RoPE (q,k) + f32 cache_k; EPI 2: f32 = acc + res
template <int EPI>
__global__ __launch_bounds__(512, 4) void kgemm(
    const u16* __restrict__ A, const u16* __restrict__ Bt, int N, int K,
    u16* o0, u16* __restrict__ o1, u16* __restrict__ o2,
    float* of, const float* res, const float* __restrict__ fc) {
  __shared__ u16 As[2][128 * 64];
  __shared__ u16 Bs[2][128 * 64];
  int bn = blockIdx.x * 128, bm = blockIdx.y * 128;
  int tid = threadIdx.x, lane = tid & 63, wv = tid >> 6;  // 8 waves
  int wm = (wv >> 2) * 64;   // 0 / 64
  int wn = (wv & 3) * 32;    // 0..96
  int r16 = lane & 15, grp = lane >> 4;
  int srow = lane >> 3;                    // 0..7: row within 8-row chunk
  int schunk = ((lane & 7) ^ srow) * 8;    // inverse-swizzled source k-offset
  f32x4 acc[4][2] = {};
  // wave wv stages rows [wv*16, wv*16+16) of both tiles
  const u16* Abase = A + (size_t)(bm + wv * 16) * K + schunk;
  const u16* Bbase = Bt + (size_t)(bn + wv * 16) * K + schunk;
  int woff = wv * 16 * 64;

  auto STAGE = [&](int buf, int k0) {
#pragma unroll
    for (int j = 0; j < 2; ++j) {
      gld16(Abase + (size_t)(j * 8 + srow) * K + k0, &As[buf][woff + j * 512]);
      gld16(Bbase + (size_t)(j * 8 + srow) * K + k0, &Bs[buf][woff + j * 512]);
    }
  };
  auto COMPUTE = [&](int buf) {
#pragma unroll
    for (int kk = 0; kk < 2; ++kk) {
      int swz = (((kk << 2) | grp) ^ (r16 & 7)) * 8;
      bf16x8 af[4], bfr[2];
#pragma unroll
      for (int m = 0; m < 4; ++m)
        af[m] = *(const bf16x8*)&As[buf][(wm + m * 16 + r16) * 64 + swz];
#pragma unroll
      for (int n = 0; n < 2; ++n)
        bfr[n] = *(const bf16x8*)&Bs[buf][(wn + n * 16 + r16) * 64 + swz];
#pragma unroll
      for (int m = 0; m < 4; ++m)
#pragma unroll
        for (int n = 0; n < 2; ++n)
          acc[m][n] = __builtin_amdgcn_mfma_f32_16x16x32_bf16(af[m], bfr[n], acc[m][n], 0, 0, 0);
    }
  };

  STAGE(0, 0);
  int nt = K >> 6;
  for (int t = 0; t < nt; ++t) {
    int cur = t & 1;
    if (t + 1 < nt) {
      STAGE(cur ^ 1, (t + 1) << 6);
      asm volatile("s_waitcnt vmcnt(4)" ::: "memory");
    } else {
      asm volatile("s_waitcnt vmcnt(0)" ::: "memory");
    }
    __builtin_amdgcn_sched_barrier(0);
    __builtin_amdgcn_s_barrier();   // tile t visible to all waves
    __builtin_amdgcn_sched_barrier(0);
    COMPUTE(cur);
    __builtin_amdgcn_s_barrier();   // all waves done reading buf[cur]
  }

  bool oddlane = (r16 & 1) != 0;
#pragma unroll
  for (int mi = 0; mi < 4; ++mi) {
#pragma unroll
    for (int ni = 0; ni < 2; ++ni) {
#pragma unroll
      for (int r = 0; r < 4; ++r) {
        int gr = bm + wm + mi * 16 + grp * 4 + r;
        int gc = bn + wn + ni * 16 + r16;
        float v = acc[mi][ni][r];
        if constexpr (EPI == 0) {
          float pv = __shfl_xor(v, 1, 64);  // partner column (pair 2j<->2j+1)
          if (gc < DIM + 512) {
            // fused RoPE: lane pair (even=x0, odd=x1)
            int s_idx = gr & (SEQ - 1);
            int jp = (gc & 127) >> 1;
            float2 cs = *(const float2*)(fc + s_idx * HD + jp * 2);
            float y;
            if (oddlane) y = pv * cs.y + v * cs.x;   // x0*sin + x1*cos
            else         y = v * cs.x - pv * cs.y;   // x0*cos - x1*sin
            if (gc < DIM) {
              o0[(size_t)gr * DIM + gc] = f2bf(y);          // q (roped)
            } else {
              int c2 = gc - DIM;
              o1[(size_t)gr * 512 + c2] = f2bf(y);          // k (roped)
              ((float*)res)[(size_t)gr * 512 + c2] = y;     // cache_k f32
            }
          } else {
            int c2 = gc - (DIM + 512);
            of[(size_t)gr * 512 + c2] = v;                  // cache_v f32
            o2[(size_t)gr * 512 + c2] = f2bf(v);            // v bf16
          }
        } else {
          of[(size_t)gr * N + gc] = v + res[(size_t)gr * N + gc];
        }
      }
    }
  }
}

// ---------- interleaved gate/up GEMM, 128x128 tile, 8 waves.
// Bt rows: 2j = wg^T[:,j], 2j+1 = wu^T[:,j]  (N_wide = 11264).
// Epilogue: lane pairs (even=gate, odd=up) exchanged via shfl_xor(1);
// even lanes store silu(g)*u.  Default blockIdx mapping (swizzle reverted).
__global__ __launch_bounds__(512, 4) void kgemm_gu(
    const u16* __restrict__ A, const u16* __restrict__ Bt,
    u16* __restrict__ out) {
  const int K = DIM;
  __shared__ u16 As[2][128 * 64];
  __shared__ u16 Bs[2][128 * 64];
  int bn = blockIdx.x * 128, bm = blockIdx.y * 128;
  int tid = threadIdx.x, lane = tid & 63, wv = tid >> 6;
  int wm = (wv >> 2) * 64;
  int wn = (wv & 3) * 32;
  int r16 = lane & 15, grp = lane >> 4;
  int srow = lane >> 3;
  int schunk = ((lane & 7) ^ srow) * 8;
  f32x4 acc[4][2] = {};
  const u16* Abase = A + (size_t)(bm + wv * 16) * K + schunk;
  const u16* Bbase = Bt + (size_t)(bn + wv * 16) * K + schunk;
  int woff = wv * 16 * 64;

  auto STAGE = [&](int buf, int k0) {
#pragma unroll
    for (int j = 0; j < 2; ++j) {
      gld16(Abase + (size_t)(j * 8 + srow) * K + k0, &As[buf][woff + j * 512]);
      gld16(Bbase + (size_t)(j * 8 + srow) * K + k0, &Bs[buf][woff + j * 512]);
    }
  };
  auto COMPUTE = [&](int buf) {
#pragma unroll
    for (int kk = 0; kk < 2; ++kk) {
      int swz = (((kk << 2) | grp) ^ (r16 & 7)) * 8;
      bf16x8 af[4], bfr[2];
#pragma unroll
      for (int m = 0; m < 4; ++m)
        af[m] = *(const bf16x8*)&As[buf][(wm + m * 16 + r16) * 64 + swz];
#pragma unroll
      for (int n = 0; n < 2; ++n)
        bfr[n] = *(const bf16x8*)&Bs[buf][(wn + n * 16 + r16) * 64 + swz];
#pragma unroll
      for (int m = 0; m < 4; ++m)
#pragma unroll
        for (int n = 0; n < 2; ++n)
          acc[m][n] = __builtin_amdgcn_mfma_f32_16x16x32_bf16(af[m], bfr[n], acc[m][n], 0, 0, 0);
    }
  };

  STAGE(0, 0);
  int nt = K >> 6;
  for (int t = 0; t < nt; ++t) {
    int cur = t & 1;
    if (t + 1 < nt) {
      STAGE(cur ^ 1, (t + 1) << 6);
      asm volatile("s_waitcnt vmcnt(4)" ::: "memory");
    } else {
      asm volatile("s_waitcnt vmcnt(0)" ::: "memory");
    }
    __builtin_amdgcn_sched_barrier(0);
    __builtin_amdgcn_s_barrier();
    __builtin_amdgcn_sched_barrier(0);
    COMPUTE(cur);
    __builtin_amdgcn_s_barrier();
  }

  bool evenlane = (r16 & 1) == 0;
#pragma unroll
  for (int mi = 0; mi < 4; ++mi) {
#pragma unroll
    for (int ni = 0; ni < 2; ++ni) {
#pragma unroll
      for (int r = 0; r < 4; ++r) {
        float v = acc[mi][ni][r];
        float pv = __shfl_xor(v, 1, 64);  // partner column (gate<->up)
        if (evenlane) {
          int gr = bm + wm + mi * 16 + grp * 4 + r;
          int gc = bn + wn + ni * 16 + r16;
          float sg = v / (1.0f + __expf(-v));
          out[(size_t)gr * FFNDIM + (gc >> 1)] = f2bf(sg * pv);
        }
      }
    }
  }
}

// ---------- causal GQA flash attention, LDS-staged K/V.
// Block = 4 waves = 64 q-rows of one (b,h); sweeps KV in 64-tiles with
// double-buffered LDS staging (counted vmcnt, GEMM-proven skeleton) and
// GEMM-proven XOR-chunk swizzle. Longest blocks dispatch first.
__global__ __launch_bounds__(256) void kattn(const u16* __restrict__ qb,
                                             const u16* __restrict__ kb,
                                             const u16* __restrict__ vtb,
                                             u16* __restrict__ ctxb) {
  __shared__ u16 Ks[2][64 * 128];   // [t_rel][d] content-swizzled
  __shared__ u16 Vs[2][128 * 64];   // [d][t_rel] content-swizzled
  __shared__ u16 Plds[4][16][72];
  int tid = threadIdx.x;
  int l = tid & 63, wv = tid >> 6;
  int qg = 15 - blockIdx.x;  // longest first
  int h = blockIdx.y, b = blockIdx.z;
  int g = h >> 2;  // J = NH/NKV = 4
  int q0 = qg * 64 + wv * 16;
  int r16 = l & 15, grp = l >> 4;
  const float scale = 0.08838834764831845f;  // 1/sqrt(128)
  bf16x8 qf[4];
  {
    const u16* qrow = qb + (size_t)(b * SEQ + q0 + r16) * DIM + h * HD + grp * 8;
#pragma unroll
    for (int c = 0; c < 4; ++c) qf[c] = *(const bf16x8*)(qrow + c * 32);
  }
  const u16* kg = kb + (size_t)b * SEQ * (NKV * HD) + g * HD;
  const u16* vg = vtb + (size_t)((b * NKV + g) * HD) * SEQ;

  // stage one 64-KV tile: K 64x128 (4 passes) + V 128x64 (4 passes), 8 gld16/thread
  auto STAGE = [&](int buf, int t0) {
#pragma unroll
    for (int p = 0; p < 4; ++p) {
      int row = p * 16 + wv * 4 + (l >> 4);          // t_rel 0..63
      int ch = (l & 15) ^ (row & 7);                 // inverse swizzle
      gld16(kg + (size_t)(t0 + row) * (NKV * HD) + ch * 8,
            &Ks[buf][p * 2048 + wv * 512]);
    }
#pragma unroll
    for (int p = 0; p < 4; ++p) {
      int row = p * 32 + wv * 8 + (l >> 3);          // d 0..127
      int ch = (l & 7) ^ (row & 7);
      gld16(vg + (size_t)row * SEQ + t0 + ch * 8,
            &Vs[buf][p * 2048 + wv * 512]);
    }
  };

  f32x4 ctx[8] = {};
  float m = -1e30f, lsum = 0.0f;
  int q_idx = q0 + r16;
  int ntiles = qg + 1;

  STAGE(0, 0);
  for (int tt = 0; tt < ntiles; ++tt) {
    int cur = tt & 1;
    if (tt + 1 < ntiles) {
      STAGE(cur ^ 1, (tt + 1) * 64);
      asm volatile("s_waitcnt vmcnt(8)" ::: "memory");
    } else {
      asm volatile("s_waitcnt vmcnt(0)" ::: "memory");
    }
    __builtin_amdgcn_sched_barrier(0);
    __builtin_amdgcn_s_barrier();   // tile tt visible
    __builtin_amdgcn_sched_barrier(0);
    int t0 = tt * 64;
    f32x4 d[4] = {{0.f, 0.f, 0.f, 0.f}, {0.f, 0.f, 0.f, 0.f},
                  {0.f, 0.f, 0.f, 0.f}, {0.f, 0.f, 0.f, 0.f}};
    __builtin_amdgcn_s_setprio(1);
#pragma unroll
    for (int c = 0; c < 4; ++c) {
#pragma unroll
      for (int ch = 0; ch < 4; ++ch) {
        int row = ch * 16 + r16;
        bf16x8 kf = *(const bf16x8*)&Ks[cur][row * 128 + (((c * 4 + grp) ^ (row & 7)) * 8)];
        d[ch] = __builtin_amdgcn_mfma_f32_16x16x32_bf16(kf, qf[c], d[ch], 0, 0, 0);
      }
    }
    __builtin_amdgcn_s_setprio(0);
    // lane holds S[q = q0+r16][t = t0 + ch*16 + grp*4 + r]
    float p[16];
    float mx = -1e30f;
#pragma unroll
    for (int ch = 0; ch < 4; ++ch) {
#pragma unroll
      for (int r = 0; r < 4; ++r) {
        int tA = t0 + ch * 16 + grp * 4 + r;
        float s = d[ch][r] * scale;
        if (tA > q_idx) s = -1e30f;
        p[ch * 4 + r] = s;
        mx = fmaxf(mx, s);
      }
    }
    mx = fmaxf(mx, __shfl_xor(mx, 16, 64));
    mx = fmaxf(mx, __shfl_xor(mx, 32, 64));
    // defer-max: skip rescale when per-tile max growth <= 8 (P bounded by e^8)
    if (!__all(mx - m <= 8.0f)) {
      float mnew = fmaxf(m, mx);
      float corr = __expf(m - mnew);
      lsum *= corr;
      float cf[4];
#pragma unroll
      for (int r = 0; r < 4; ++r) cf[r] = __shfl(corr, grp * 4 + r, 64);
#pragma unroll
      for (int dc = 0; dc < 8; ++dc)
#pragma unroll
        for (int r = 0; r < 4; ++r) ctx[dc][r] *= cf[r];
      m = mnew;
    }
    float psum = 0.f;
#pragma unroll
    for (int i = 0; i < 16; ++i) {
      p[i] = __expf(p[i] - m);
      psum += p[i];
    }
    psum += __shfl_xor(psum, 16, 64);
    psum += __shfl_xor(psum, 32, 64);
    lsum += psum;
    // P -> per-wave LDS slab [q][t_rel]
#pragma unroll
    for (int ch = 0; ch < 4; ++ch) {
      unsigned w0 = (unsigned)f2bf(p[ch * 4]) | ((unsigned)f2bf(p[ch * 4 + 1]) << 16);
      unsigned w1 = (unsigned)f2bf(p[ch * 4 + 2]) | ((unsigned)f2bf(p[ch * 4 + 3]) << 16);
      *(unsigned*)&Plds[wv][r16][ch * 16 + grp * 4] = w0;
      *(unsigned*)&Plds[wv][r16][ch * 16 + grp * 4 + 2] = w1;
    }
    bf16x8 pa0, pa1;
    {
      union { bf16x8 v; int4 q; } u0, u1;
      u0.q = *(const int4*)&Plds[wv][r16][grp * 8];
      u1.q = *(const int4*)&Plds[wv][r16][32 + grp * 8];
      pa0 = u0.v;
      pa1 = u1.v;
    }
    __builtin_amdgcn_s_setprio(1);
#pragma unroll
    for (int dc = 0; dc < 8; ++dc) {
      int row = dc * 16 + r16;
      bf16x8 vf0 = *(const bf16x8*)&Vs[cur][row * 64 + ((grp ^ (row & 7)) * 8)];
      bf16x8 vf1 = *(const bf16x8*)&Vs[cur][row * 64 + (((grp + 4) ^ (row & 7)) * 8)];
      ctx[dc] = __builtin_amdgcn_mfma_f32_16x16x32_bf16(pa0, vf0, ctx[dc], 0, 0, 0);
      ctx[dc] = __builtin_amdgcn_mfma_f32_16x16x32_bf16(pa1, vf1, ctx[dc], 0, 0, 0);
    }
    __builtin_amdgcn_s_setprio(0);
    __builtin_amdgcn_s_barrier();   // all waves done reading Ks/Vs[cur]
  }
  float linv = 1.0f / lsum;
  float lf[4];
#pragma unroll
  for (int r = 0; r < 4; ++r) lf[r] = __shfl(linv, grp * 4 + r, 64);
  u16* crow = ctxb + (size_t)(b * SEQ + q0) * DIM + h * HD;
#pragma unroll
  for (int dc = 0; dc < 8; ++dc)
#pragma unroll
    for (int r = 0; r < 4; ++r)
      crow[(size_t)(grp * 4 + r) * DIM + dc * 16 + r16] = f2bf(ctx[dc][r] * lf[r]);
}

extern "C" void kernel_launch(void* const* d_in, const int* in_sizes, int n_in,
                              void* d_out, int out_size, void* d_ws, size_t ws_size,
                              hipStream_t stream) {
  const float* x = (const float*)d_in[0];
  const float* fc = (const float*)d_in[1];
  const float* wq = (const float*)d_in[5];
  const float* wk = (const float*)d_in[6];
  const float* wv = (const float*)d_in[7];
  const float* wo = (const float*)d_in[8];
  const float* wg = (const float*)d_in[9];
  const float* wu = (const float*)d_in[10];
  const float* wd = (const float*)d_in[11];
  const float* anw = (const float*)d_in[12];
  const float* fnw = (const float*)d_in[13];

  float* out_x = (float*)d_out;                       // [2048][2048] f32
  float* out_ck = out_x + (size_t)MROWS * DIM;        // [2048][512] f32
  float* out_cv = out_ck + (size_t)MROWS * NKV * HD;  // [2048][512] f32

  char* ws = (char*)d_ws;
  u16* h_b    = (u16*)(ws);                      // 8 MB   [2048][2048] bf16
  u16* q_b    = (u16*)(ws + (8u << 20));         // 8 MB   [2048][2048]
  u16* k_b    = (u16*)(ws + (16u << 20));        // 2 MB   [2048][512]
  u16* v_b    = (u16*)(ws + (18u << 20));        // 2 MB   [2048][512]
  u16* ctx_b  = (u16*)(ws + (20u << 20));        // 8 MB   [2048][2048]
  u16* hf_b   = (u16*)(ws + (28u << 20));        // 8 MB   [2048][2048]
  u16* Wt     = (u16*)(ws + (60u << 20));        // 12 MB  qkv^T, later wo^T
  u16* vt_b   = h_b;                             // reuse (attn phase)
  u16* Wt_gu  = (u16*)(ws + (36u << 20));        // 44 MB  [11264][2048] interleaved
  u16* g_b    = (u16*)(ws);                      // 22 MB  silu*up (post-attn)
  u16* Wt_dn  = (u16*)(ws + (36u << 20));        // 22 MB  wd^T (post-gu)

  // QKV weights -> Wt rows [0,2048)=wq^T, [2048,2560)=wk^T, [2560,3072)=wv^T
  kxpose<<<dim3(2048 / 64, 2048 / 64), 256, 0, stream>>>(wq, Wt, 2048, 2048, 1, 0);
  kxpose<<<dim3(512 / 64, 2048 / 64), 256, 0, stream>>>(wk, Wt + (size_t)2048 * 2048, 2048, 512, 1, 0);
  kxpose<<<dim3(512 / 64, 2048 / 64), 256, 0, stream>>>(wv, Wt + (size_t)2560 * 2048, 2048, 512, 1, 0);

  krmsnorm<<<MROWS, 256, 0, stream>>>(x, anw, h_b);
  // QKV GEMM with fused RoPE (q,k) + f32 cache writes (res slot carries out_ck)
  kgemm<0><<<dim3(3072 / 128, 16), 512, 0, stream>>>(h_b, Wt, 3072, 2048,
                                                     q_b, k_b, v_b, out_cv, out_ck, fc);
  kvxpose<<<dim3(SEQ / 64, HD / 64, BSZ * NKV), 256, 0, stream>>>(v_b, vt_b);
  kattn<<<dim3(SEQ / 64, NH, BSZ), 256, 0, stream>>>(q_b, k_b, vt_b, ctx_b);

  kxpose<<<dim3(32, 32), 256, 0, stream>>>(wo, Wt, 2048, 2048, 1, 0);
  kgemm<2><<<dim3(16, 16), 512, 0, stream>>>(ctx_b, Wt, 2048, 2048,
                                             nullptr, nullptr, nullptr, out_x, x, nullptr);
  krmsnorm<<<MROWS, 256, 0, stream>>>(out_x, fnw, hf_b);

  // FFN: interleaved gate/up -> fused swiglu epilogue -> down
  kxpose<<<dim3(5632 / 64, 2048 / 64), 256, 0, stream>>>(wg, Wt_gu, 2048, 5632, 2, 0);
  kxpose<<<dim3(5632 / 64, 2048 / 64), 256, 0, stream>>>(wu, Wt_gu, 2048, 5632, 2, 1);
  kgemm_gu<<<dim3(11264 / 128, 16), 512, 0, stream>>>(hf_b, Wt_gu, g_b);
  kxpose<<<dim3(2048 / 64, 5632 / 64), 256, 0, stream>>>(wd, Wt_dn, 5632, 2048, 1, 0);
  kgemm<2><<<dim3(16, 16), 512, 0, stream>>>(g_b, Wt_dn, 2048, 5632,
                                             nullptr, nullptr, nullptr, out_x, out_x, nullptr);
}

// Round 13
// 372.250 us; speedup vs baseline: 1.0718x; 1.0150x over previous
//
#include <hip/hip_runtime.h>

typedef float f32x4 __attribute__((ext_vector_type(4)));
typedef __bf16 bf16x8 __attribute__((ext_vector_type(8)));
typedef unsigned short u16;

#define DIM 2048
#define SEQ 1024
#define BSZ 2
#define NH 16
#define NKV 4
#define HD 128
#define FFNDIM 5632
#define MROWS (BSZ * SEQ)  // 2048

__device__ __forceinline__ u16 f2bf(float f) {
  union { float f; unsigned u; } v; v.f = f;
  unsigned u = v.u;
  unsigned r = (u + 0x7fffu + ((u >> 16) & 1u)) >> 16;  // RNE
  return (u16)r;
}
__device__ __forceinline__ float bf2f(u16 h) {
  union { unsigned u; float f; } v; v.u = ((unsigned)h) << 16; return v.f;
}

__device__ __forceinline__ void gld16(const void* g, void* l) {
  __builtin_amdgcn_global_load_lds(
      (const __attribute__((address_space(1))) unsigned int*)g,
      (__attribute__((address_space(3))) unsigned int*)l, 16, 0, 0);
}

// ---------- transpose + fp32->bf16 convert: W [K][N] f32 -> Wt[(n*rs+ro)][K] bf16
// Vectorized: float4 reads, uint2 (4x bf16) writes; pitch-65 LDS (<=2-way banks).
__global__ __launch_bounds__(256) void kxpose(const float* __restrict__ W,
                                              u16* __restrict__ Wt,
                                              int K, int N, int rs, int ro) {
  __shared__ float t[64][65];
  int kb = blockIdx.y * 64, nb = blockIdx.x * 64;
  int tid = threadIdx.x;
#pragma unroll
  for (int it = 0; it < 4; ++it) {
    int idx = it * 256 + tid;
    int r = idx >> 4, c4 = (idx & 15) * 4;
    float4 v = *(const float4*)(W + (size_t)(kb + r) * N + nb + c4);
    t[r][c4] = v.x; t[r][c4 + 1] = v.y; t[r][c4 + 2] = v.z; t[r][c4 + 3] = v.w;
  }
  __syncthreads();
#pragma unroll
  for (int it = 0; it < 4; ++it) {
    int idx = it * 256 + tid;
    int rn = idx >> 4, ck4 = (idx & 15) * 4;
    u16 o[4];
#pragma unroll
    for (int j = 0; j < 4; ++j) o[j] = f2bf(t[ck4 + j][rn]);
    *(uint2*)(Wt + ((size_t)(nb + rn) * rs + ro) * K + kb + ck4) = *(const uint2*)o;
  }
}

// ---------- RMSNorm: x [rows][2048] f32 -> out bf16
__global__ __launch_bounds__(256) void krmsnorm(const float* __restrict__ x,
                                                const float* __restrict__ w,
                                                u16* __restrict__ out) {
  int row = blockIdx.x, tid = threadIdx.x;
  const float* xr = x + (size_t)row * DIM;
  float4 a = *(const float4*)(xr + tid * 8);
  float4 b = *(const float4*)(xr + tid * 8 + 4);
  float ss = a.x * a.x + a.y * a.y + a.z * a.z + a.w * a.w +
             b.x * b.x + b.y * b.y + b.z * b.z + b.w * b.w;
#pragma unroll
  for (int off = 1; off < 64; off <<= 1) ss += __shfl_xor(ss, off, 64);
  __shared__ float red[4];
  if ((tid & 63) == 0) red[tid >> 6] = ss;
  __syncthreads();
  float tot = red[0] + red[1] + red[2] + red[3];
  float sc = rsqrtf(tot * (1.0f / DIM) + 1e-5f);
  float xs[8] = {a.x, a.y, a.z, a.w, b.x, b.y, b.z, b.w};
  const float* wr = w + tid * 8;
  u16 o[8];
#pragma unroll
  for (int j = 0; j < 8; ++j) o[j] = f2bf(xs[j] * sc * wr[j]);
  *(int4*)(out + (size_t)row * DIM + tid * 8) = *(const int4*)o;
}

// ---------- GEMM 128x128, 8 waves (2Mx4N, wave tile 64x32):
// C[2048][N] = A[2048][K](bf16) * Bt[N][K](bf16)^T
// Counted-vmcnt pipeline + XOR-swizzled LDS (validated r5-r12).
// EPI 0: qkv-route, FUSED RoPE (q,k) + f32 cache_k + direct Vt write (o2);
// EPI 2: f32 = acc + res
template <int EPI>
__global__ __launch_bounds__(512, 4) void kgemm(
    const u16* __restrict__ A, const u16* __restrict__ Bt, int N, int K,
    u16* o0, u16* __restrict__ o1, u16* __restrict__ o2,
    float* of, const float* res, const float* __restrict__ fc) {
  __shared__ u16 As[2][128 * 64];
  __shared__ u16 Bs[2][128 * 64];
  int bn = blockIdx.x * 128, bm = blockIdx.y * 128;
  int tid = threadIdx.x, lane = tid & 63, wv = tid >> 6;  // 8 waves
  int wm = (wv >> 2) * 64;   // 0 / 64
  int wn = (wv & 3) * 32;    // 0..96
  int r16 = lane & 15, grp = lane >> 4;
  int srow = lane >> 3;                    // 0..7: row within 8-row chunk
  int schunk = ((lane & 7) ^ srow) * 8;    // inverse-swizzled source k-offset
  f32x4 acc[4][2] = {};
  // wave wv stages rows [wv*16, wv*16+16) of both tiles
  const u16* Abase = A + (size_t)(bm + wv * 16) * K + schunk;
  const u16* Bbase = Bt + (size_t)(bn + wv * 16) * K + schunk;
  int woff = wv * 16 * 64;

  auto STAGE = [&](int buf, int k0) {
#pragma unroll
    for (int j = 0; j < 2; ++j) {
      gld16(Abase + (size_t)(j * 8 + srow) * K + k0, &As[buf][woff + j * 512]);
      gld16(Bbase + (size_t)(j * 8 + srow) * K + k0, &Bs[buf][woff + j * 512]);
    }
  };
  auto COMPUTE = [&](int buf) {
#pragma unroll
    for (int kk = 0; kk < 2; ++kk) {
      int swz = (((kk << 2) | grp) ^ (r16 & 7)) * 8;
      bf16x8 af[4], bfr[2];
#pragma unroll
      for (int m = 0; m < 4; ++m)
        af[m] = *(const bf16x8*)&As[buf][(wm + m * 16 + r16) * 64 + swz];
#pragma unroll
      for (int n = 0; n < 2; ++n)
        bfr[n] = *(const bf16x8*)&Bs[buf][(wn + n * 16 + r16) * 64 + swz];
#pragma unroll
      for (int m = 0; m < 4; ++m)
#pragma unroll
        for (int n = 0; n < 2; ++n)
          acc[m][n] = __builtin_amdgcn_mfma_f32_16x16x32_bf16(af[m], bfr[n], acc[m][n], 0, 0, 0);
    }
  };

  STAGE(0, 0);
  int nt = K >> 6;
  for (int t = 0; t < nt; ++t) {
    int cur = t & 1;
    if (t + 1 < nt) {
      STAGE(cur ^ 1, (t + 1) << 6);
      asm volatile("s_waitcnt vmcnt(4)" ::: "memory");
    } else {
      asm volatile("s_waitcnt vmcnt(0)" ::: "memory");
    }
    __builtin_amdgcn_sched_barrier(0);
    __builtin_amdgcn_s_barrier();   // tile t visible to all waves
    __builtin_amdgcn_sched_barrier(0);
    COMPUTE(cur);
    __builtin_amdgcn_s_barrier();   // all waves done reading buf[cur]
  }

  bool oddlane = (r16 & 1) != 0;
#pragma unroll
  for (int mi = 0; mi < 4; ++mi) {
#pragma unroll
    for (int ni = 0; ni < 2; ++ni) {
      if constexpr (EPI == 0) {
        int gc = bn + wn + ni * 16 + r16;   // whole wave in one 16-col window
        int gr0 = bm + wm + mi * 16 + grp * 4;
        if (gc < DIM + 512) {
          // fused RoPE: lane pair (even=x0, odd=x1)
          int s0 = gr0 & (SEQ - 1);
          int jp = (gc & 127) >> 1;
#pragma unroll
          for (int r = 0; r < 4; ++r) {
            float v = acc[mi][ni][r];
            float pv = __shfl_xor(v, 1, 64);
            float2 cs = *(const float2*)(fc + (s0 + r) * HD + jp * 2);
            float y;
            if (oddlane) y = pv * cs.y + v * cs.x;   // x0*sin + x1*cos
            else         y = v * cs.x - pv * cs.y;   // x0*cos - x1*sin
            int gr = gr0 + r;
            if (gc < DIM) {
              o0[(size_t)gr * DIM + gc] = f2bf(y);          // q (roped)
            } else {
              int c2 = gc - DIM;
              o1[(size_t)gr * 512 + c2] = f2bf(y);          // k (roped)
              ((float*)res)[(size_t)gr * 512 + c2] = y;     // cache_k f32
            }
          }
        } else {
          // v-range: f32 cache_v + direct transposed Vt[b][g][d][s] (uint2)
          int c2 = gc - (DIM + 512);
          int g = c2 >> 7, d = c2 & 127;
          int b = gr0 >> 10, s0 = gr0 & (SEQ - 1);
          u16 o4[4];
#pragma unroll
          for (int r = 0; r < 4; ++r) {
            float v = acc[mi][ni][r];
            of[(size_t)(gr0 + r) * 512 + c2] = v;           // cache_v f32
            o4[r] = f2bf(v);
          }
          *(uint2*)(o2 + ((size_t)(b * NKV + g) * HD + d) * SEQ + s0) = *(const uint2*)o4;
        }
      } else {
#pragma unroll
        for (int r = 0; r < 4; ++r) {
          int gr = bm + wm + mi * 16 + grp * 4 + r;
          int gc = bn + wn + ni * 16 + r16;
          of[(size_t)gr * N + gc] = acc[mi][ni][r] + res[(size_t)gr * N + gc];
        }
      }
    }
  }
}

// ---------- interleaved gate/up GEMM, 128x128 tile, 8 waves.
// Bt rows: 2j = wg^T[:,j], 2j+1 = wu^T[:,j]  (N_wide = 11264).
// Epilogue: lane pairs (even=gate, odd=up) exchanged via shfl_xor(1);
// even lanes store silu(g)*u.
__global__ __launch_bounds__(512, 4) void kgemm_gu(
    const u16* __restrict__ A, const u16* __restrict__ Bt,
    u16* __restrict__ out) {
  const int K = DIM;
  __shared__ u16 As[2][128 * 64];
  __shared__ u16 Bs[2][128 * 64];
  int bn = blockIdx.x * 128, bm = blockIdx.y * 128;
  int tid = threadIdx.x, lane = tid & 63, wv = tid >> 6;
  int wm = (wv >> 2) * 64;
  int wn = (wv & 3) * 32;
  int r16 = lane & 15, grp = lane >> 4;
  int srow = lane >> 3;
  int schunk = ((lane & 7) ^ srow) * 8;
  f32x4 acc[4][2] = {};
  const u16* Abase = A + (size_t)(bm + wv * 16) * K + schunk;
  const u16* Bbase = Bt + (size_t)(bn + wv * 16) * K + schunk;
  int woff = wv * 16 * 64;

  auto STAGE = [&](int buf, int k0) {
#pragma unroll
    for (int j = 0; j < 2; ++j) {
      gld16(Abase + (size_t)(j * 8 + srow) * K + k0, &As[buf][woff + j * 512]);
      gld16(Bbase + (size_t)(j * 8 + srow) * K + k0, &Bs[buf][woff + j * 512]);
    }
  };
  auto COMPUTE = [&](int buf) {
#pragma unroll
    for (int kk = 0; kk < 2; ++kk) {
      int swz = (((kk << 2) | grp) ^ (r16 & 7)) * 8;
      bf16x8 af[4], bfr[2];
#pragma unroll
      for (int m = 0; m < 4; ++m)
        af[m] = *(const bf16x8*)&As[buf][(wm + m * 16 + r16) * 64 + swz];
#pragma unroll
      for (int n = 0; n < 2; ++n)
        bfr[n] = *(const bf16x8*)&Bs[buf][(wn + n * 16 + r16) * 64 + swz];
#pragma unroll
      for (int m = 0; m < 4; ++m)
#pragma unroll
        for (int n = 0; n < 2; ++n)
          acc[m][n] = __builtin_amdgcn_mfma_f32_16x16x32_bf16(af[m], bfr[n], acc[m][n], 0, 0, 0);
    }
  };

  STAGE(0, 0);
  int nt = K >> 6;
  for (int t = 0; t < nt; ++t) {
    int cur = t & 1;
    if (t + 1 < nt) {
      STAGE(cur ^ 1, (t + 1) << 6);
      asm volatile("s_waitcnt vmcnt(4)" ::: "memory");
    } else {
      asm volatile("s_waitcnt vmcnt(0)" ::: "memory");
    }
    __builtin_amdgcn_sched_barrier(0);
    __builtin_amdgcn_s_barrier();
    __builtin_amdgcn_sched_barrier(0);
    COMPUTE(cur);
    __builtin_amdgcn_s_barrier();
  }

  bool evenlane = (r16 & 1) == 0;
#pragma unroll
  for (int mi = 0; mi < 4; ++mi) {
#pragma unroll
    for (int ni = 0; ni < 2; ++ni) {
#pragma unroll
      for (int r = 0; r < 4; ++r) {
        float v = acc[mi][ni][r];
        float pv = __shfl_xor(v, 1, 64);  // partner column (gate<->up)
        if (evenlane) {
          int gr = bm + wm + mi * 16 + grp * 4 + r;
          int gc = bn + wn + ni * 16 + r16;
          float sg = v / (1.0f + __expf(-v));
          out[(size_t)gr * FFNDIM + (gc >> 1)] = f2bf(sg * pv);
        }
      }
    }
  }
}

// ---------- causal GQA flash attention, LDS-staged K/V.
// Block = 4 waves = 64 q-rows of one (b,h); sweeps KV in 64-tiles with
// double-buffered LDS staging (counted vmcnt, GEMM-proven skeleton) and
// GEMM-proven XOR-chunk swizzle. Longest blocks dispatch first.
__global__ __launch_bounds__(256) void kattn(const u16* __restrict__ qb,
                                             const u16* __restrict__ kb,
                                             const u16* __restrict__ vtb,
                                             u16* __restrict__ ctxb) {
  __shared__ u16 Ks[2][64 * 128];   // [t_rel][d] content-swizzled
  __shared__ u16 Vs[2][128 * 64];   // [d][t_rel] content-swizzled
  __shared__ u16 Plds[4][16][72];
  int tid = threadIdx.x;
  int l = tid & 63, wv = tid >> 6;
  int qg = 15 - blockIdx.x;  // longest first
  int h = blockIdx.y, b = blockIdx.z;
  int g = h >> 2;  // J = NH/NKV = 4
  int q0 = qg * 64 + wv * 16;
  int r16 = l & 15, grp = l >> 4;
  const float scale = 0.08838834764831845f;  // 1/sqrt(128)
  bf16x8 qf[4];
  {
    const u16* qrow = qb + (size_t)(b * SEQ + q0 + r16) * DIM + h * HD + grp * 8;
#pragma unroll
    for (int c = 0; c < 4; ++c) qf[c] = *(const bf16x8*)(qrow + c * 32);
  }
  const u16* kg = kb + (size_t)b * SEQ * (NKV * HD) + g * HD;
  const u16* vg = vtb + (size_t)((b * NKV + g) * HD) * SEQ;

  // stage one 64-KV tile: K 64x128 (4 passes) + V 128x64 (4 passes), 8 gld16/thread
  auto STAGE = [&](int buf, int t0) {
#pragma unroll
    for (int p = 0; p < 4; ++p) {
      int row = p * 16 + wv * 4 + (l >> 4);          // t_rel 0..63
      int ch = (l & 15) ^ (row & 7);                 // inverse swizzle
      gld16(kg + (size_t)(t0 + row) * (NKV * HD) + ch * 8,
            &Ks[buf][p * 2048 + wv * 512]);
    }
#pragma unroll
    for (int p = 0; p < 4; ++p) {
      int row = p * 32 + wv * 8 + (l >> 3);          // d 0..127
      int ch = (l & 7) ^ (row & 7);
      gld16(vg + (size_t)row * SEQ + t0 + ch * 8,
            &Vs[buf][p * 2048 + wv * 512]);
    }
  };

  f32x4 ctx[8] = {};
  float m = -1e30f, lsum = 0.0f;
  int q_idx = q0 + r16;
  int ntiles = qg + 1;

  STAGE(0, 0);
  for (int tt = 0; tt < ntiles; ++tt) {
    int cur = tt & 1;
    if (tt + 1 < ntiles) {
      STAGE(cur ^ 1, (tt + 1) * 64);
      asm volatile("s_waitcnt vmcnt(8)" ::: "memory");
    } else {
      asm volatile("s_waitcnt vmcnt(0)" ::: "memory");
    }
    __builtin_amdgcn_sched_barrier(0);
    __builtin_amdgcn_s_barrier();   // tile tt visible
    __builtin_amdgcn_sched_barrier(0);
    int t0 = tt * 64;
    f32x4 d[4] = {{0.f, 0.f, 0.f, 0.f}, {0.f, 0.f, 0.f, 0.f},
                  {0.f, 0.f, 0.f, 0.f}, {0.f, 0.f, 0.f, 0.f}};
    __builtin_amdgcn_s_setprio(1);
#pragma unroll
    for (int c = 0; c < 4; ++c) {
#pragma unroll
      for (int ch = 0; ch < 4; ++ch) {
        int row = ch * 16 + r16;
        bf16x8 kf = *(const bf16x8*)&Ks[cur][row * 128 + (((c * 4 + grp) ^ (row & 7)) * 8)];
        d[ch] = __builtin_amdgcn_mfma_f32_16x16x32_bf16(kf, qf[c], d[ch], 0, 0, 0);
      }
    }
    __builtin_amdgcn_s_setprio(0);
    // lane holds S[q = q0+r16][t = t0 + ch*16 + grp*4 + r]
    float p[16];
    float mx = -1e30f;
#pragma unroll
    for (int ch = 0; ch < 4; ++ch) {
#pragma unroll
      for (int r = 0; r < 4; ++r) {
        int tA = t0 + ch * 16 + grp * 4 + r;
        float s = d[ch][r] * scale;
        if (tA > q_idx) s = -1e30f;
        p[ch * 4 + r] = s;
        mx = fmaxf(mx, s);
      }
    }
    mx = fmaxf(mx, __shfl_xor(mx, 16, 64));
    mx = fmaxf(mx, __shfl_xor(mx, 32, 64));
    // defer-max: skip rescale when per-tile max growth <= 8 (P bounded by e^8)
    if (!__all(mx - m <= 8.0f)) {
      float mnew = fmaxf(m, mx);
      float corr = __expf(m - mnew);
      lsum *= corr;
      float cf[4];
#pragma unroll
      for (int r = 0; r < 4; ++r) cf[r] = __shfl(corr, grp * 4 + r, 64);
#pragma unroll
      for (int dc = 0; dc < 8; ++dc)
#pragma unroll
        for (int r = 0; r < 4; ++r) ctx[dc][r] *= cf[r];
      m = mnew;
    }
    float psum = 0.f;
#pragma unroll
    for (int i = 0; i < 16; ++i) {
      p[i] = __expf(p[i] - m);
      psum += p[i];
    }
    psum += __shfl_xor(psum, 16, 64);
    psum += __shfl_xor(psum, 32, 64);
    lsum += psum;
    // P -> per-wave LDS slab [q][t_rel]
#pragma unroll
    for (int ch = 0; ch < 4; ++ch) {
      unsigned w0 = (unsigned)f2bf(p[ch * 4]) | ((unsigned)f2bf(p[ch * 4 + 1]) << 16);
      unsigned w1 = (unsigned)f2bf(p[ch * 4 + 2]) | ((unsigned)f2bf(p[ch * 4 + 3]) << 16);
      *(unsigned*)&Plds[wv][r16][ch * 16 + grp * 4] = w0;
      *(unsigned*)&Plds[wv][r16][ch * 16 + grp * 4 + 2] = w1;
    }
    bf16x8 pa0, pa1;
    {
      union { bf16x8 v; int4 q; } u0, u1;
      u0.q = *(const int4*)&Plds[wv][r16][grp * 8];
      u1.q = *(const int4*)&Plds[wv][r16][32 + grp * 8];
      pa0 = u0.v;
      pa1 = u1.v;
    }
    __builtin_amdgcn_s_setprio(1);
#pragma unroll
    for (int dc = 0; dc < 8; ++dc) {
      int row = dc * 16 + r16;
      bf16x8 vf0 = *(const bf16x8*)&Vs[cur][row * 64 + ((grp ^ (row & 7)) * 8)];
      bf16x8 vf1 = *(const bf16x8*)&Vs[cur][row * 64 + (((grp + 4) ^ (row & 7)) * 8)];
      ctx[dc] = __builtin_amdgcn_mfma_f32_16x16x32_bf16(pa0, vf0, ctx[dc], 0, 0, 0);
      ctx[dc] = __builtin_amdgcn_mfma_f32_16x16x32_bf16(pa1, vf1, ctx[dc], 0, 0, 0);
    }
    __builtin_amdgcn_s_setprio(0);
    __builtin_amdgcn_s_barrier();   // all waves done reading Ks/Vs[cur]
  }
  float linv = 1.0f / lsum;
  float lf[4];
#pragma unroll
  for (int r = 0; r < 4; ++r) lf[r] = __shfl(linv, grp * 4 + r, 64);
  u16* crow = ctxb + (size_t)(b * SEQ + q0) * DIM + h * HD;
#pragma unroll
  for (int dc = 0; dc < 8; ++dc)
#pragma unroll
    for (int r = 0; r < 4; ++r)
      crow[(size_t)(grp * 4 + r) * DIM + dc * 16 + r16] = f2bf(ctx[dc][r] * lf[r]);
}

extern "C" void kernel_launch(void* const* d_in, const int* in_sizes, int n_in,
                              void* d_out, int out_size, void* d_ws, size_t ws_size,
                              hipStream_t stream) {
  const float* x = (const float*)d_in[0];
  const float* fc = (const float*)d_in[1];
  const float* wq = (const float*)d_in[5];
  const float* wk = (const float*)d_in[6];
  const float* wv = (const float*)d_in[7];
  const float* wo = (const float*)d_in[8];
  const float* wg = (const float*)d_in[9];
  const float* wu = (const float*)d_in[10];
  const float* wd = (const float*)d_in[11];
  const float* anw = (const float*)d_in[12];
  const float* fnw = (const float*)d_in[13];

  float* out_x = (float*)d_out;                       // [2048][2048] f32
  float* out_ck = out_x + (size_t)MROWS * DIM;        // [2048][512] f32
  float* out_cv = out_ck + (size_t)MROWS * NKV * HD;  // [2048][512] f32

  char* ws = (char*)d_ws;
  u16* h_b    = (u16*)(ws);                      // 8 MB   [2048][2048] bf16
  u16* q_b    = (u16*)(ws + (8u << 20));         // 8 MB   [2048][2048]
  u16* k_b    = (u16*)(ws + (16u << 20));        // 2 MB   [2048][512]
  u16* ctx_b  = (u16*)(ws + (20u << 20));        // 8 MB   [2048][2048]
  u16* vt_b   = (u16*)(ws + (28u << 20));        // 2 MB   Vt (dead region until hf)
  u16* hf_b   = (u16*)(ws + (28u << 20));        // 8 MB   [2048][2048] (post-attn)
  u16* Wt     = (u16*)(ws + (60u << 20));        // 12 MB  qkv^T, later wo^T
  u16* Wt_gu  = (u16*)(ws + (36u << 20));        // 44 MB  [11264][2048] interleaved
  u16* g_b    = (u16*)(ws);                      // 22 MB  silu*up (post-attn)
  u16* Wt_dn  = (u16*)(ws + (36u << 20));        // 22 MB  wd^T (post-gu)

  // QKV weights -> Wt rows [0,2048)=wq^T, [2048,2560)=wk^T, [2560,3072)=wv^T
  kxpose<<<dim3(2048 / 64, 2048 / 64), 256, 0, stream>>>(wq, Wt, 2048, 2048, 1, 0);
  kxpose<<<dim3(512 / 64, 2048 / 64), 256, 0, stream>>>(wk, Wt + (size_t)2048 * 2048, 2048, 512, 1, 0);
  kxpose<<<dim3(512 / 64, 2048 / 64), 256, 0, stream>>>(wv, Wt + (size_t)2560 * 2048, 2048, 512, 1, 0);

  krmsnorm<<<MROWS, 256, 0, stream>>>(x, anw, h_b);
  // QKV GEMM: fused RoPE (q,k), f32 cache writes, direct Vt (o2 = vt_b)
  kgemm<0><<<dim3(3072 / 128, 16), 512, 0, stream>>>(h_b, Wt, 3072, 2048,
                                                     q_b, k_b, vt_b, out_cv, out_ck, fc);
  kattn<<<dim3(SEQ / 64, NH, BSZ), 256, 0, stream>>>(q_b, k_b, vt_b, ctx_b);

  kxpose<<<dim3(32, 32), 256, 0, stream>>>(wo, Wt, 2048, 2048, 1, 0);
  kgemm<2><<<dim3(16, 16), 512, 0, stream>>>(ctx_b, Wt, 2048, 2048,
                                             nullptr, nullptr, nullptr, out_x, x, nullptr);
  krmsnorm<<<MROWS, 256, 0, stream>>>(out_x, fnw, hf_b);

  // FFN: interleaved gate/up -> fused swiglu epilogue -> down
  kxpose<<<dim3(5632 / 64, 2048 / 64), 256, 0, stream>>>(wg, Wt_gu, 2048, 5632, 2, 0);
  kxpose<<<dim3(5632 / 64, 2048 / 64), 256, 0, stream>>>(wu, Wt_gu, 2048, 5632, 2, 1);
  kgemm_gu<<<dim3(11264 / 128, 16), 512, 0, stream>>>(hf_b, Wt_gu, g_b);
  kxpose<<<dim3(2048 / 64, 5632 / 64), 256, 0, stream>>>(wd, Wt_dn, 5632, 2048, 1, 0);
  kgemm<2><<<dim3(16, 16), 512, 0, stream>>>(g_b, Wt_dn, 2048, 5632,
                                             nullptr, nullptr, nullptr, out_x, out_x, nullptr);
}